// Round 1
// baseline (1930.178 us; speedup 1.0000x reference)
//
#include <hip/hip_runtime.h>
#include <cstdint>
#include <cstddef>

#define T_TOKENS 8192
#define HDIM 2048
#define IDIM 2048
#define TWO_I 4096
#define NE 8
#define BM 128
#define BK 32

typedef __attribute__((ext_vector_type(8))) short short8;
typedef __attribute__((ext_vector_type(4))) float f32x4;

__device__ __forceinline__ unsigned short f2bf(float f) {
    union { float f; unsigned int u; } v; v.f = f;
    unsigned int u = v.u;
    u += 0x7fffu + ((u >> 16) & 1u);   // RNE
    return (unsigned short)(u >> 16);
}

__device__ __forceinline__ void gload_lds16(const unsigned short* g, unsigned short* l) {
    __builtin_amdgcn_global_load_lds(
        (const __attribute__((address_space(1))) unsigned int*)(g),
        (__attribute__((address_space(3))) unsigned int*)(l), 16, 0, 0);
}

// ---------------- gating: logits -> top2 -> softmax ----------------
__global__ __launch_bounds__(256) void k_gate(const float* __restrict__ x,
                                              const float* __restrict__ gw,
                                              const float* __restrict__ gb,
                                              int* __restrict__ tok_e,
                                              float* __restrict__ tok_w,
                                              int* __restrict__ counts) {
    __shared__ float gwl[NE * HDIM];   // 64KB
    for (int i = threadIdx.x; i < NE * HDIM / 4; i += 256)
        ((float4*)gwl)[i] = ((const float4*)gw)[i];
    __syncthreads();
    int wid = threadIdx.x >> 6, lane = threadIdx.x & 63;
    int nw = gridDim.x * 4;
    for (int t = blockIdx.x * 4 + wid; t < T_TOKENS; t += nw) {
        float acc[NE];
#pragma unroll
        for (int e = 0; e < NE; e++) acc[e] = 0.f;
        const float* xr = x + (size_t)t * HDIM;
        for (int i = lane; i < HDIM; i += 64) {
            float xv = xr[i];
#pragma unroll
            for (int e = 0; e < NE; e++) acc[e] += xv * gwl[e * HDIM + i];
        }
#pragma unroll
        for (int e = 0; e < NE; e++) {
#pragma unroll
            for (int off = 32; off; off >>= 1) acc[e] += __shfl_xor(acc[e], off);
        }
        if (lane == 0) {
            float lg[NE];
#pragma unroll
            for (int e = 0; e < NE; e++) lg[e] = acc[e] + gb[e];
            int i0 = 0;
#pragma unroll
            for (int e = 1; e < NE; e++) if (lg[e] > lg[i0]) i0 = e;
            int i1 = (i0 == 0) ? 1 : 0;
#pragma unroll
            for (int e = 0; e < NE; e++) if (e != i0 && lg[e] > lg[i1]) i1 = e;
            float e1 = __expf(lg[i1] - lg[i0]);
            float s = 1.f + e1;
            tok_e[t * 2 + 0] = i0; tok_e[t * 2 + 1] = i1;
            tok_w[t * 2 + 0] = 1.f / s; tok_w[t * 2 + 1] = e1 / s;
            atomicAdd(&counts[i0], 1);
            atomicAdd(&counts[i1], 1);
        }
    }
}

__global__ void k_prefix(const int* __restrict__ counts, int* __restrict__ base,
                         int* __restrict__ tb) {
    if (threadIdx.x == 0) {
        int b = 0, t = 0;
        for (int e = 0; e < NE; e++) {
            base[e] = b; tb[e] = t;
            b += counts[e];
            t += (counts[e] + BM - 1) / BM;
        }
        base[NE] = b; tb[NE] = t;
    }
}

__global__ __launch_bounds__(256) void k_scatter(const int* __restrict__ tok_e,
                                                 const float* __restrict__ tok_w,
                                                 const int* __restrict__ base,
                                                 int* __restrict__ cursor,
                                                 int* __restrict__ slot_tok,
                                                 float* __restrict__ slot_w) {
    int t = blockIdx.x * 256 + threadIdx.x;
    if (t >= T_TOKENS) return;
#pragma unroll
    for (int k = 0; k < 2; k++) {
        int e = tok_e[t * 2 + k];
        int p = atomicAdd(&cursor[e], 1);
        int s = base[e] + p;
        slot_tok[s] = t;
        slot_w[s] = tok_w[t * 2 + k];
    }
}

__global__ __launch_bounds__(256) void k_convert(const float* __restrict__ x,
                                                 unsigned short* __restrict__ xb) {
    int i = blockIdx.x * 256 + threadIdx.x;   // one float4 per thread
    float4 v = ((const float4*)x)[i];
    union { unsigned short s[4]; uint2 u; } o;
    o.s[0] = f2bf(v.x); o.s[1] = f2bf(v.y); o.s[2] = f2bf(v.z); o.s[3] = f2bf(v.w);
    ((uint2*)xb)[i] = o.u;
}

// ---------------- GEMM1: h = x@w1^T + b1, fused SwiGLU -> Y (bf16) ----------------
// Block tile: 128 rows x 64 y-cols (=128 h-cols). Grid: (m-tile) x 32 n-tiles.
__global__ __launch_bounds__(256) void k_gemm1(const unsigned short* __restrict__ Xb,
                                               const float* __restrict__ w1,
                                               const float* __restrict__ b1,
                                               const int* __restrict__ slot_tok,
                                               const int* __restrict__ base,
                                               const int* __restrict__ tb,
                                               unsigned short* __restrict__ Y) {
    int g = blockIdx.x >> 5;
    int nt = blockIdx.x & 31;
    if (g >= tb[NE]) return;
    int e = 0;
    while (tb[e + 1] <= g) e++;
    int mt = g - tb[e];
    int slot0 = base[e] + mt * BM;
    int cnt = base[e + 1] - base[e];
    int mrows = cnt - mt * BM; if (mrows > BM) mrows = BM;

    __shared__ unsigned short Al[BM * BK];   // 8KB
    __shared__ unsigned short Bg[64 * BK];   // 4KB (GLU rows)
    __shared__ unsigned short Bq[64 * BK];   // 4KB (LIN rows)
    __shared__ int stok[BM];

    int tid = threadIdx.x;
    if (tid < BM) {
        int s = slot0 + tid;
        if (s > T_TOKENS * 2 - 1) s = T_TOKENS * 2 - 1;
        stok[tid] = slot_tok[s];
    }
    __syncthreads();

    // A staging: chunk c = j*256+tid, m=c>>2, kc=c&3  (16B per lane, lane-linear LDS)
    const unsigned short* aSrc[2];
    unsigned short* aDst[2];
#pragma unroll
    for (int j = 0; j < 2; j++) {
        int c = j * 256 + tid;
        int m = c >> 2, kc = c & 3;
        aSrc[j] = Xb + (size_t)stok[m] * HDIM + kc * 8;
        aDst[j] = &Al[c * 8];
    }

    // B staging: 16 bf16 per thread; tid<128 -> Bg, else Bq
    int isl = tid >> 7;
    int nl = (tid & 127) >> 1;
    int kcb = tid & 1;
    int c0 = nt * 64;
    const float* bSrc = w1 + (size_t)e * TWO_I * HDIM +
                        (size_t)(2 * (c0 + nl) + isl) * HDIM + kcb * 16;
    unsigned short* bDst = (isl ? Bq : Bg) + nl * BK + kcb * 16;

    int wid = tid >> 6, lane = tid & 63;
    int wm = (wid & 1) * 64, wn = (wid >> 1) * 32;
    int arow = lane & 15, akq = (lane >> 4) * 8;

    f32x4 accg[4][2], accl[4][2];
#pragma unroll
    for (int mi = 0; mi < 4; mi++)
#pragma unroll
        for (int ni = 0; ni < 2; ni++) { accg[mi][ni] = (f32x4)0.f; accl[mi][ni] = (f32x4)0.f; }

    for (int k0 = 0; k0 < HDIM; k0 += BK) {
        gload_lds16(aSrc[0] + k0, aDst[0]);
        gload_lds16(aSrc[1] + k0, aDst[1]);
        const float4* p = (const float4*)(bSrc + k0);
        float4 v0 = p[0], v1 = p[1], v2 = p[2], v3 = p[3];
        union { unsigned short s[8]; uint4 q; } pk0, pk1;
        pk0.s[0] = f2bf(v0.x); pk0.s[1] = f2bf(v0.y); pk0.s[2] = f2bf(v0.z); pk0.s[3] = f2bf(v0.w);
        pk0.s[4] = f2bf(v1.x); pk0.s[5] = f2bf(v1.y); pk0.s[6] = f2bf(v1.z); pk0.s[7] = f2bf(v1.w);
        pk1.s[0] = f2bf(v2.x); pk1.s[1] = f2bf(v2.y); pk1.s[2] = f2bf(v2.z); pk1.s[3] = f2bf(v2.w);
        pk1.s[4] = f2bf(v3.x); pk1.s[5] = f2bf(v3.y); pk1.s[6] = f2bf(v3.z); pk1.s[7] = f2bf(v3.w);
        *(uint4*)(bDst) = pk0.q;
        *(uint4*)(bDst + 8) = pk1.q;
        __syncthreads();

        short8 af[4];
#pragma unroll
        for (int mi = 0; mi < 4; mi++)
            af[mi] = *(const short8*)&Al[(wm + mi * 16 + arow) * BK + akq];
#pragma unroll
        for (int ni = 0; ni < 2; ni++) {
            short8 bg = *(const short8*)&Bg[(wn + ni * 16 + arow) * BK + akq];
            short8 bl = *(const short8*)&Bq[(wn + ni * 16 + arow) * BK + akq];
#pragma unroll
            for (int mi = 0; mi < 4; mi++) {
                accg[mi][ni] = __builtin_amdgcn_mfma_f32_16x16x32_bf16(af[mi], bg, accg[mi][ni], 0, 0, 0);
                accl[mi][ni] = __builtin_amdgcn_mfma_f32_16x16x32_bf16(af[mi], bl, accl[mi][ni], 0, 0, 0);
            }
        }
        __syncthreads();
    }

    const float* b1e = b1 + (size_t)e * TWO_I;
#pragma unroll
    for (int ni = 0; ni < 2; ni++) {
        int cg = c0 + wn + ni * 16 + arow;
        float bg_ = b1e[2 * cg], bl_ = b1e[2 * cg + 1];
#pragma unroll
        for (int mi = 0; mi < 4; mi++) {
#pragma unroll
            for (int r = 0; r < 4; r++) {
                int m = wm + mi * 16 + (lane >> 4) * 4 + r;
                if (m < mrows) {
                    float gv = accg[mi][ni][r] + bg_;
                    float lv = accl[mi][ni][r] + bl_;
                    float yv = gv * (1.f / (1.f + __expf(-1.702f * gv))) * (lv + 1.f);
                    Y[(size_t)(slot0 + m) * IDIM + cg] = f2bf(yv);
                }
            }
        }
    }
}

// ---------------- GEMM2: out += w * (Y@w2^T + b2) ----------------
// Block tile: 128 rows x 128 cols. Grid: (m-tile) x 16 n-tiles.
__global__ __launch_bounds__(256) void k_gemm2(const unsigned short* __restrict__ Y,
                                               const float* __restrict__ w2,
                                               const float* __restrict__ b2,
                                               const int* __restrict__ slot_tok,
                                               const float* __restrict__ slot_w,
                                               const int* __restrict__ base,
                                               const int* __restrict__ tb,
                                               float* __restrict__ out) {
    int g = blockIdx.x >> 4;
    int nt = blockIdx.x & 15;
    if (g >= tb[NE]) return;
    int e = 0;
    while (tb[e + 1] <= g) e++;
    int mt = g - tb[e];
    int slot0 = base[e] + mt * BM;
    int cnt = base[e + 1] - base[e];
    int mrows = cnt - mt * BM; if (mrows > BM) mrows = BM;

    __shared__ unsigned short Al[BM * BK];   // 8KB
    __shared__ unsigned short Bl[BM * BK];   // 8KB
    __shared__ int stok[BM];
    __shared__ float swt[BM];

    int tid = threadIdx.x;
    if (tid < BM) {
        int s = slot0 + tid;
        if (s > T_TOKENS * 2 - 1) s = T_TOKENS * 2 - 1;
        stok[tid] = slot_tok[s];
        swt[tid] = slot_w[s];
    }

    const unsigned short* aSrc[2];
    unsigned short* aDst[2];
#pragma unroll
    for (int j = 0; j < 2; j++) {
        int c = j * 256 + tid;
        int m = c >> 2, kc = c & 3;
        int s = slot0 + m;
        if (s > T_TOKENS * 2 - 1) s = T_TOKENS * 2 - 1;
        aSrc[j] = Y + (size_t)s * IDIM + kc * 8;
        aDst[j] = &Al[c * 8];
    }

    int nb = tid >> 1, kcb = tid & 1;
    const float* bSrc = w2 + (size_t)e * HDIM * IDIM + (size_t)(nt * 128 + nb) * IDIM + kcb * 16;
    unsigned short* bDst = &Bl[nb * BK + kcb * 16];

    int wid = tid >> 6, lane = tid & 63;
    int wm = (wid & 1) * 64, wn = (wid >> 1) * 64;
    int arow = lane & 15, akq = (lane >> 4) * 8;

    f32x4 acc[4][4];
#pragma unroll
    for (int mi = 0; mi < 4; mi++)
#pragma unroll
        for (int ni = 0; ni < 4; ni++) acc[mi][ni] = (f32x4)0.f;

    for (int k0 = 0; k0 < IDIM; k0 += BK) {
        gload_lds16(aSrc[0] + k0, aDst[0]);
        gload_lds16(aSrc[1] + k0, aDst[1]);
        const float4* p = (const float4*)(bSrc + k0);
        float4 v0 = p[0], v1 = p[1], v2 = p[2], v3 = p[3];
        union { unsigned short s[8]; uint4 q; } pk0, pk1;
        pk0.s[0] = f2bf(v0.x); pk0.s[1] = f2bf(v0.y); pk0.s[2] = f2bf(v0.z); pk0.s[3] = f2bf(v0.w);
        pk0.s[4] = f2bf(v1.x); pk0.s[5] = f2bf(v1.y); pk0.s[6] = f2bf(v1.z); pk0.s[7] = f2bf(v1.w);
        pk1.s[0] = f2bf(v2.x); pk1.s[1] = f2bf(v2.y); pk1.s[2] = f2bf(v2.z); pk1.s[3] = f2bf(v2.w);
        pk1.s[4] = f2bf(v3.x); pk1.s[5] = f2bf(v3.y); pk1.s[6] = f2bf(v3.z); pk1.s[7] = f2bf(v3.w);
        *(uint4*)(bDst) = pk0.q;
        *(uint4*)(bDst + 8) = pk1.q;
        __syncthreads();

        short8 af[4], bf[4];
#pragma unroll
        for (int mi = 0; mi < 4; mi++)
            af[mi] = *(const short8*)&Al[(wm + mi * 16 + arow) * BK + akq];
#pragma unroll
        for (int ni = 0; ni < 4; ni++)
            bf[ni] = *(const short8*)&Bl[(wn + ni * 16 + arow) * BK + akq];
#pragma unroll
        for (int mi = 0; mi < 4; mi++)
#pragma unroll
            for (int ni = 0; ni < 4; ni++)
                acc[mi][ni] = __builtin_amdgcn_mfma_f32_16x16x32_bf16(af[mi], bf[ni], acc[mi][ni], 0, 0, 0);
        __syncthreads();
    }

    const float* b2e = b2 + (size_t)e * HDIM;
#pragma unroll
    for (int ni = 0; ni < 4; ni++) {
        int col = nt * 128 + wn + ni * 16 + arow;
        float bv = b2e[col];
#pragma unroll
        for (int mi = 0; mi < 4; mi++) {
#pragma unroll
            for (int r = 0; r < 4; r++) {
                int m = wm + mi * 16 + (lane >> 4) * 4 + r;
                if (m < mrows) {
                    float val = (acc[mi][ni][r] + bv) * swt[m];
                    atomicAdd(&out[(size_t)stok[m] * HDIM + col], val);
                }
            }
        }
    }
}

extern "C" void kernel_launch(void* const* d_in, const int* in_sizes, int n_in,
                              void* d_out, int out_size, void* d_ws, size_t ws_size,
                              hipStream_t stream) {
    const float* x  = (const float*)d_in[0];
    const float* gw = (const float*)d_in[1];
    const float* gb = (const float*)d_in[2];
    const float* w1 = (const float*)d_in[3];
    const float* b1 = (const float*)d_in[4];
    const float* w2 = (const float*)d_in[5];
    const float* b2 = (const float*)d_in[6];
    float* out = (float*)d_out;

    char* w = (char*)d_ws;
    int* counts = (int*)w;          // 8
    int* cursor = counts + 8;       // 8
    int* base   = counts + 16;      // 9
    int* tb     = counts + 32;      // 9
    int* tok_e    = (int*)(w + 256);
    float* tok_w  = (float*)(w + 256 + 65536);
    int* slot_tok = (int*)(w + 256 + 131072);
    float* slot_w = (float*)(w + 256 + 196608);
    unsigned short* Xb = (unsigned short*)(w + 262400);
    unsigned short* Y  = (unsigned short*)(w + 262400 + 33554432);

    hipMemsetAsync(d_ws, 0, 256, stream);
    hipMemsetAsync(d_out, 0, (size_t)out_size * sizeof(float), stream);

    hipLaunchKernelGGL(k_gate, dim3(64), dim3(256), 0, stream, x, gw, gb, tok_e, tok_w, counts);
    hipLaunchKernelGGL(k_convert, dim3(T_TOKENS * HDIM / 4 / 256), dim3(256), 0, stream, x, Xb);
    hipLaunchKernelGGL(k_prefix, dim3(1), dim3(64), 0, stream, counts, base, tb);
    hipLaunchKernelGGL(k_scatter, dim3(T_TOKENS / 256), dim3(256), 0, stream,
                       tok_e, tok_w, base, cursor, slot_tok, slot_w);
    hipLaunchKernelGGL(k_gemm1, dim3(135 * 32), dim3(256), 0, stream,
                       Xb, w1, b1, slot_tok, base, tb, Y);
    hipLaunchKernelGGL(k_gemm2, dim3(135 * 16), dim3(256), 0, stream,
                       Y, w2, b2, slot_tok, slot_w, base, tb, out);
}

// Round 2
// 1424.467 us; speedup vs baseline: 1.3550x; 1.3550x over previous
//
#include <hip/hip_runtime.h>
#include <cstdint>
#include <cstddef>

#define T_TOKENS 8192
#define NSLOT (T_TOKENS * 2)
#define HDIM 2048
#define IDIM 2048
#define TWO_I 4096
#define NE 8
#define BM 128
#define BK 32

typedef __attribute__((ext_vector_type(8))) short short8;
typedef __attribute__((ext_vector_type(4))) float f32x4;

__device__ __forceinline__ unsigned short f2bf(float f) {
    union { float f; unsigned int u; } v; v.f = f;
    unsigned int u = v.u;
    u += 0x7fffu + ((u >> 16) & 1u);   // RNE
    return (unsigned short)(u >> 16);
}

__device__ __forceinline__ void gload_lds16(const unsigned short* g, unsigned short* l) {
    __builtin_amdgcn_global_load_lds(
        (const __attribute__((address_space(1))) unsigned int*)(g),
        (__attribute__((address_space(3))) unsigned int*)(l), 16, 0, 0);
}

// ---------------- gating: logits -> top2 -> softmax ----------------
__global__ __launch_bounds__(256) void k_gate(const float* __restrict__ x,
                                              const float* __restrict__ gw,
                                              const float* __restrict__ gb,
                                              int* __restrict__ tok_e,
                                              float* __restrict__ tok_w,
                                              int* __restrict__ counts) {
    __shared__ float gwl[NE * HDIM];   // 64KB
    for (int i = threadIdx.x; i < NE * HDIM / 4; i += 256)
        ((float4*)gwl)[i] = ((const float4*)gw)[i];
    __syncthreads();
    int wid = threadIdx.x >> 6, lane = threadIdx.x & 63;
    int gwave = blockIdx.x * 4 + wid;            // 1024 waves
    for (int t = gwave; t < T_TOKENS; t += 1024) {
        float acc[NE];
#pragma unroll
        for (int e = 0; e < NE; e++) acc[e] = 0.f;
        const float4* xr = (const float4*)(x + (size_t)t * HDIM);
#pragma unroll
        for (int i0 = 0; i0 < HDIM / 4 / 64; i0++) {
            int i = i0 * 64 + lane;
            float4 xv = xr[i];
#pragma unroll
            for (int e = 0; e < NE; e++) {
                float4 gv = ((const float4*)gwl)[e * (HDIM / 4) + i];
                acc[e] += xv.x * gv.x + xv.y * gv.y + xv.z * gv.z + xv.w * gv.w;
            }
        }
#pragma unroll
        for (int e = 0; e < NE; e++) {
#pragma unroll
            for (int off = 32; off; off >>= 1) acc[e] += __shfl_xor(acc[e], off);
        }
        if (lane == 0) {
            float lg[NE];
#pragma unroll
            for (int e = 0; e < NE; e++) lg[e] = acc[e] + gb[e];
            int i0 = 0;
#pragma unroll
            for (int e = 1; e < NE; e++) if (lg[e] > lg[i0]) i0 = e;
            int i1 = (i0 == 0) ? 1 : 0;
#pragma unroll
            for (int e = 0; e < NE; e++) if (e != i0 && lg[e] > lg[i1]) i1 = e;
            float e1 = __expf(lg[i1] - lg[i0]);
            float s = 1.f + e1;
            tok_e[t * 2 + 0] = i0; tok_e[t * 2 + 1] = i1;
            tok_w[t * 2 + 0] = 1.f / s; tok_w[t * 2 + 1] = e1 / s;
            atomicAdd(&counts[i0], 1);
            atomicAdd(&counts[i1], 1);
        }
    }
}

__global__ void k_prefix(const int* __restrict__ counts, int* __restrict__ base,
                         int* __restrict__ tb) {
    if (threadIdx.x == 0) {
        int b = 0, t = 0;
        for (int e = 0; e < NE; e++) {
            base[e] = b; tb[e] = t;
            b += counts[e];
            t += (counts[e] + BM - 1) / BM;
        }
        base[NE] = b; tb[NE] = t;
    }
}

__global__ __launch_bounds__(256) void k_scatter(const int* __restrict__ tok_e,
                                                 const float* __restrict__ tok_w,
                                                 const int* __restrict__ base,
                                                 int* __restrict__ cursor,
                                                 int* __restrict__ slot_tok,
                                                 int* __restrict__ slot_of) {
    int t = blockIdx.x * 256 + threadIdx.x;
    if (t >= T_TOKENS) return;
#pragma unroll
    for (int k = 0; k < 2; k++) {
        int e = tok_e[t * 2 + k];
        int p = atomicAdd(&cursor[e], 1);
        int s = base[e] + p;
        slot_tok[s] = t;
        slot_of[t * 2 + k] = s;
    }
}

__global__ __launch_bounds__(256) void k_convert(const float* __restrict__ src,
                                                 unsigned short* __restrict__ dst) {
    int i = blockIdx.x * 256 + threadIdx.x;   // one float4 per thread
    float4 v = ((const float4*)src)[i];
    union { unsigned short s[4]; uint2 u; } o;
    o.s[0] = f2bf(v.x); o.s[1] = f2bf(v.y); o.s[2] = f2bf(v.z); o.s[3] = f2bf(v.w);
    ((uint2*)dst)[i] = o.u;
}

// ---------------- GEMM1: h = x@w1^T + b1, fused SwiGLU -> Y (bf16) ----------------
// Block tile: 128 token-rows x 64 y-cols (=128 h-rows of W1). Grid: m-tile x 32 n-tiles.
// All staging via global_load_lds (A gathered per-slot, B from pre-converted bf16 W1).
__global__ __launch_bounds__(256) void k_gemm1(const unsigned short* __restrict__ Xb,
                                               const unsigned short* __restrict__ W1b,
                                               const float* __restrict__ b1,
                                               const int* __restrict__ slot_tok,
                                               const int* __restrict__ base,
                                               const int* __restrict__ tb,
                                               unsigned short* __restrict__ Y) {
    int g = blockIdx.x >> 5;
    int nt = blockIdx.x & 31;
    if (g >= tb[NE]) return;
    int e = 0;
    while (tb[e + 1] <= g) e++;
    int mt = g - tb[e];
    int slot0 = base[e] + mt * BM;
    int mrows = base[e + 1] - base[e] - mt * BM; if (mrows > BM) mrows = BM;

    __shared__ unsigned short Al[BM * BK];   // 8KB
    __shared__ unsigned short Bg[64 * BK];   // 4KB (GLU rows, even)
    __shared__ unsigned short Bq[64 * BK];   // 4KB (LIN rows, odd)
    __shared__ int stok[BM];

    int tid = threadIdx.x;
    if (tid < BM) {
        int s = slot0 + tid;
        if (s > NSLOT - 1) s = NSLOT - 1;
        stok[tid] = slot_tok[s];
    }
    __syncthreads();

    int wid = tid >> 6, lane = tid & 63;
    int c0 = nt * 64;
    const size_t eoff = (size_t)e * TWO_I * HDIM;

    // 16 KB staged per k-iter = 1024 x 16B chunks = 4 glds per wave.
    const unsigned short* gsrc[4];
    unsigned short* ldst[4];
#pragma unroll
    for (int j = 0; j < 4; j++) {
        int c = (wid * 4 + j) * 64 + lane;
        if (c < 512) {            // A: m = c>>2, kc = c&3
            int m = c >> 2, kc = c & 3;
            gsrc[j] = Xb + (size_t)stok[m] * HDIM + kc * 8;
            ldst[j] = &Al[c * 8];
        } else if (c < 768) {     // B even rows (GLU)
            int cb = c - 512, r = cb >> 2, kc = cb & 3;
            gsrc[j] = W1b + eoff + (size_t)(2 * (c0 + r)) * HDIM + kc * 8;
            ldst[j] = &Bg[cb * 8];
        } else {                  // B odd rows (LIN)
            int cq = c - 768, r = cq >> 2, kc = cq & 3;
            gsrc[j] = W1b + eoff + (size_t)(2 * (c0 + r) + 1) * HDIM + kc * 8;
            ldst[j] = &Bq[cq * 8];
        }
    }

    int wm = (wid & 1) * 64, wn = (wid >> 1) * 32;
    int arow = lane & 15, akq = (lane >> 4) * 8;

    f32x4 accg[4][2], accl[4][2];
#pragma unroll
    for (int mi = 0; mi < 4; mi++)
#pragma unroll
        for (int ni = 0; ni < 2; ni++) { accg[mi][ni] = (f32x4)0.f; accl[mi][ni] = (f32x4)0.f; }

    for (int k0 = 0; k0 < HDIM; k0 += BK) {
#pragma unroll
        for (int j = 0; j < 4; j++) gload_lds16(gsrc[j] + k0, ldst[j]);
        __syncthreads();

        short8 af[4];
#pragma unroll
        for (int mi = 0; mi < 4; mi++)
            af[mi] = *(const short8*)&Al[(wm + mi * 16 + arow) * BK + akq];
#pragma unroll
        for (int ni = 0; ni < 2; ni++) {
            short8 bg = *(const short8*)&Bg[(wn + ni * 16 + arow) * BK + akq];
            short8 bl = *(const short8*)&Bq[(wn + ni * 16 + arow) * BK + akq];
#pragma unroll
            for (int mi = 0; mi < 4; mi++) {
                accg[mi][ni] = __builtin_amdgcn_mfma_f32_16x16x32_bf16(af[mi], bg, accg[mi][ni], 0, 0, 0);
                accl[mi][ni] = __builtin_amdgcn_mfma_f32_16x16x32_bf16(af[mi], bl, accl[mi][ni], 0, 0, 0);
            }
        }
        __syncthreads();
    }

    const float* b1e = b1 + (size_t)e * TWO_I;
#pragma unroll
    for (int ni = 0; ni < 2; ni++) {
        int cg = c0 + wn + ni * 16 + arow;
        float bg_ = b1e[2 * cg], bl_ = b1e[2 * cg + 1];
#pragma unroll
        for (int mi = 0; mi < 4; mi++) {
#pragma unroll
            for (int r = 0; r < 4; r++) {
                int m = wm + mi * 16 + (lane >> 4) * 4 + r;
                if (m < mrows) {
                    float gv = accg[mi][ni][r] + bg_;
                    float lv = accl[mi][ni][r] + bl_;
                    float yv = gv * (1.f / (1.f + __expf(-1.702f * gv))) * (lv + 1.f);
                    Y[(size_t)(slot0 + m) * IDIM + cg] = f2bf(yv);
                }
            }
        }
    }
}

// ---------------- GEMM2: Y2[slot] = Y@w2^T + b2 (unweighted, no atomics) ----------------
// Block tile: 128 rows x 128 cols. Grid: m-tile x 16 n-tiles.
__global__ __launch_bounds__(256) void k_gemm2(const unsigned short* __restrict__ Y,
                                               const unsigned short* __restrict__ W2b,
                                               const float* __restrict__ b2,
                                               const int* __restrict__ base,
                                               const int* __restrict__ tb,
                                               float* __restrict__ Y2) {
    int g = blockIdx.x >> 4;
    int nt = blockIdx.x & 15;
    if (g >= tb[NE]) return;
    int e = 0;
    while (tb[e + 1] <= g) e++;
    int mt = g - tb[e];
    int slot0 = base[e] + mt * BM;
    int mrows = base[e + 1] - base[e] - mt * BM; if (mrows > BM) mrows = BM;

    __shared__ unsigned short Al[BM * BK];   // 8KB
    __shared__ unsigned short Bl[BM * BK];   // 8KB

    int tid = threadIdx.x;
    int wid = tid >> 6, lane = tid & 63;
    const size_t eoff = (size_t)e * HDIM * IDIM;

    const unsigned short* gsrc[4];
    unsigned short* ldst[4];
#pragma unroll
    for (int j = 0; j < 4; j++) {
        int c = (wid * 4 + j) * 64 + lane;
        if (c < 512) {            // A: consecutive slot rows of Y (no gather needed)
            int m = c >> 2, kc = c & 3;
            int s = slot0 + m; if (s > NSLOT - 1) s = NSLOT - 1;
            gsrc[j] = Y + (size_t)s * IDIM + kc * 8;
            ldst[j] = &Al[c * 8];
        } else {                  // B: rows of W2b
            int cb = c - 512, r = cb >> 2, kc = cb & 3;
            gsrc[j] = W2b + eoff + (size_t)(nt * 128 + r) * IDIM + kc * 8;
            ldst[j] = &Bl[cb * 8];
        }
    }

    int wm = (wid & 1) * 64, wn = (wid >> 1) * 64;
    int arow = lane & 15, akq = (lane >> 4) * 8;

    f32x4 acc[4][4];
#pragma unroll
    for (int mi = 0; mi < 4; mi++)
#pragma unroll
        for (int ni = 0; ni < 4; ni++) acc[mi][ni] = (f32x4)0.f;

    for (int k0 = 0; k0 < IDIM; k0 += BK) {
#pragma unroll
        for (int j = 0; j < 4; j++) gload_lds16(gsrc[j] + k0, ldst[j]);
        __syncthreads();

        short8 af[4], bf[4];
#pragma unroll
        for (int mi = 0; mi < 4; mi++)
            af[mi] = *(const short8*)&Al[(wm + mi * 16 + arow) * BK + akq];
#pragma unroll
        for (int ni = 0; ni < 4; ni++)
            bf[ni] = *(const short8*)&Bl[(wn + ni * 16 + arow) * BK + akq];
#pragma unroll
        for (int mi = 0; mi < 4; mi++)
#pragma unroll
            for (int ni = 0; ni < 4; ni++)
                acc[mi][ni] = __builtin_amdgcn_mfma_f32_16x16x32_bf16(af[mi], bf[ni], acc[mi][ni], 0, 0, 0);
        __syncthreads();
    }

    const float* b2e = b2 + (size_t)e * HDIM;
#pragma unroll
    for (int ni = 0; ni < 4; ni++) {
        int col = nt * 128 + wn + ni * 16 + arow;
        float bv = b2e[col];
#pragma unroll
        for (int mi = 0; mi < 4; mi++) {
#pragma unroll
            for (int r = 0; r < 4; r++) {
                int m = wm + mi * 16 + (lane >> 4) * 4 + r;
                if (m < mrows)
                    Y2[(size_t)(slot0 + m) * HDIM + col] = acc[mi][ni][r] + bv;
            }
        }
    }
}

// ---------------- combine: out[t] = w0*Y2[s0] + w1*Y2[s1] ----------------
__global__ __launch_bounds__(256) void k_combine(const float* __restrict__ Y2,
                                                 const int* __restrict__ slot_of,
                                                 const float* __restrict__ tok_w,
                                                 float* __restrict__ out) {
    int t = blockIdx.x;
    int s0 = slot_of[t * 2], s1 = slot_of[t * 2 + 1];
    float w0 = tok_w[t * 2], w1 = tok_w[t * 2 + 1];
    const float4* r0 = (const float4*)(Y2 + (size_t)s0 * HDIM);
    const float4* r1 = (const float4*)(Y2 + (size_t)s1 * HDIM);
    float4* o = (float4*)(out + (size_t)t * HDIM);
#pragma unroll
    for (int it = 0; it < HDIM / 4 / 256; it++) {
        int i = it * 256 + threadIdx.x;
        float4 a = r0[i], b = r1[i];
        float4 v;
        v.x = w0 * a.x + w1 * b.x;
        v.y = w0 * a.y + w1 * b.y;
        v.z = w0 * a.z + w1 * b.z;
        v.w = w0 * a.w + w1 * b.w;
        o[i] = v;
    }
}

extern "C" void kernel_launch(void* const* d_in, const int* in_sizes, int n_in,
                              void* d_out, int out_size, void* d_ws, size_t ws_size,
                              hipStream_t stream) {
    const float* x  = (const float*)d_in[0];
    const float* gw = (const float*)d_in[1];
    const float* gb = (const float*)d_in[2];
    const float* w1 = (const float*)d_in[3];
    const float* b1 = (const float*)d_in[4];
    const float* w2 = (const float*)d_in[5];
    const float* b2 = (const float*)d_in[6];
    float* out = (float*)d_out;

    char* w = (char*)d_ws;
    int* counts = (int*)w;          // 8
    int* cursor = counts + 8;       // 8
    int* base   = counts + 16;      // 9
    int* tb     = counts + 32;      // 9
    int* tok_e    = (int*)(w + 4096);
    float* tok_w  = (float*)(w + 4096 + 65536);
    int* slot_tok = (int*)(w + 4096 + 131072);
    int* slot_of  = (int*)(w + 4096 + 196608);

    size_t off = 1 << 20;
    unsigned short* Xb  = (unsigned short*)(w + off); off += (size_t)T_TOKENS * HDIM * 2;   // 33.5 MB
    unsigned short* Y   = (unsigned short*)(w + off); off += (size_t)NSLOT * IDIM * 2;      // 67 MB
    unsigned short* W1b = (unsigned short*)(w + off); off += (size_t)NE * TWO_I * HDIM * 2; // 134 MB
    unsigned short* W2b = (unsigned short*)(w + off); off += (size_t)NE * HDIM * IDIM * 2;  // 67 MB
    float*          Y2  = (float*)(w + off);          off += (size_t)NSLOT * HDIM * 4;      // 134 MB

    hipMemsetAsync(d_ws, 0, 256, stream);

    hipLaunchKernelGGL(k_gate, dim3(256), dim3(256), 0, stream, x, gw, gb, tok_e, tok_w, counts);
    hipLaunchKernelGGL(k_convert, dim3(T_TOKENS * HDIM / 4 / 256), dim3(256), 0, stream, x, Xb);
    hipLaunchKernelGGL(k_convert, dim3(NE * TWO_I * HDIM / 4 / 256), dim3(256), 0, stream, w1, W1b);
    hipLaunchKernelGGL(k_convert, dim3(NE * HDIM * IDIM / 4 / 256), dim3(256), 0, stream, w2, W2b);
    hipLaunchKernelGGL(k_prefix, dim3(1), dim3(64), 0, stream, counts, base, tb);
    hipLaunchKernelGGL(k_scatter, dim3(T_TOKENS / 256), dim3(256), 0, stream,
                       tok_e, tok_w, base, cursor, slot_tok, slot_of);
    hipLaunchKernelGGL(k_gemm1, dim3(135 * 32), dim3(256), 0, stream,
                       Xb, W1b, b1, slot_tok, base, tb, Y);
    hipLaunchKernelGGL(k_gemm2, dim3(135 * 16), dim3(256), 0, stream,
                       Y, W2b, b2, base, tb, Y2);
    hipLaunchKernelGGL(k_combine, dim3(T_TOKENS), dim3(256), 0, stream,
                       Y2, slot_of, tok_w, out);
}